// Round 6
// baseline (255.583 us; speedup 1.0000x reference)
//
#include <hip/hip_runtime.h>
#include <math.h>

// FastLearnableEMA: y[b,t,c] = cumsum_t(x * w) / max(a^t, 1e-8)
//   a = clamp(sigmoid(logit_alpha), 1e-4, 1-1e-4)      [C]
//   w[t] = a^t * (t==0 ? 1 : (1-a))
// B=32, T=2048, C=512, fp32. HBM floor = 268 MB (~43 us @ copy-rate).
//
// R6 theory: reads were latency-bound at <=16 waves/CU (R1/R3/R5 all ~2.8
// TB/s; harness fill does 6.8, m13 copy 6.3 at full occupancy). This round:
// TB=16 -> 2048 blocks for the streaming kernels (8 blocks/CU) with
// __launch_bounds__(256,6) (24 waves/CU, VGPR cap ~85).

#define B_   32
#define T_   2048
#define C_   512
#define TB   16
#define NTB  (T_ / TB)   // 128 chunks

typedef float f32x4 __attribute__((ext_vector_type(4)));

__device__ __forceinline__ float clamp_sig(float z) {
    float a = 1.0f / (1.0f + expf(-z));
    return fminf(fmaxf(a, 1e-4f), 1.0f - 1e-4f);
}

// block: 256 thr = 2 t-chunks x 128 c-quads (512 ch);  grid: 32 b x 64 pairs
__global__ __launch_bounds__(256, 6)
void ema_partials(const float* __restrict__ x,
                  const float* __restrict__ la,
                  float* __restrict__ ws) {
    const int tid = threadIdx.x;
    const int ct  = tid & 127;
    const int cs  = tid >> 7;
    const int b   = blockIdx.x >> 6;
    const int pr  = blockIdx.x & 63;
    const int tb  = (pr << 1) | cs;
    const int c0  = ct << 2;
    const int t0  = tb * TB;

    const float4 z4 = *(const float4*)(la + c0);
    const float zz[4] = {z4.x, z4.y, z4.z, z4.w};
    float a[4], oma[4], ap[4];
    #pragma unroll
    for (int j = 0; j < 4; ++j) {
        a[j]   = clamp_sig(zz[j]);
        oma[j] = 1.0f - a[j];
        ap[j]  = exp2f((float)t0 * log2f(a[j]));   // a^t0 (underflow->0 ok)
    }

    const float4* __restrict__ xp =
        (const float4*)(x + ((size_t)b * T_ + t0) * C_ + c0);
    float s[4] = {0.f, 0.f, 0.f, 0.f};
    #pragma unroll 8
    for (int i = 0; i < TB; ++i) {
        const float4 xv = xp[(size_t)i * (C_ >> 2)];
        const bool z0 = (t0 + i) == 0;
        s[0] = fmaf(xv.x, z0 ? 1.0f : ap[0] * oma[0], s[0]);
        s[1] = fmaf(xv.y, z0 ? 1.0f : ap[1] * oma[1], s[1]);
        s[2] = fmaf(xv.z, z0 ? 1.0f : ap[2] * oma[2], s[2]);
        s[3] = fmaf(xv.w, z0 ? 1.0f : ap[3] * oma[3], s[3]);
        #pragma unroll
        for (int j = 0; j < 4; ++j) ap[j] *= a[j];
    }
    *(float4*)(ws + (size_t)(b * NTB + tb) * C_ + c0) =
        make_float4(s[0], s[1], s[2], s[3]);
}

// 16384 threads; thread owns column (b,c) of ws; exclusive scan in place.
// 4 groups of 32 INDEPENDENT loads -> latency = 4 round trips, not 128.
__global__ __launch_bounds__(256, 4)
void ema_scanws(float* __restrict__ ws) {
    const int g = blockIdx.x * 256 + threadIdx.x;
    const int b = g >> 9, c = g & (C_ - 1);
    float* __restrict__ p = ws + (size_t)b * NTB * C_ + c;
    float run = 0.0f;
    #pragma unroll 1
    for (int gr = 0; gr < 4; ++gr) {
        float v[32];
        float* __restrict__ q = p + (size_t)(gr * 32) * C_;
        #pragma unroll
        for (int k = 0; k < 32; ++k) v[k] = q[(size_t)k * C_];
        #pragma unroll
        for (int k = 0; k < 32; ++k) {
            q[(size_t)k * C_] = run;
            run += v[k];
        }
    }
}

__global__ __launch_bounds__(256, 6)
void ema_apply(const float* __restrict__ x,
               const float* __restrict__ la,
               const float* __restrict__ ws,
               float* __restrict__ y) {
    const int tid = threadIdx.x;
    const int ct  = tid & 127;
    const int cs  = tid >> 7;
    const int b   = blockIdx.x >> 6;
    const int pr  = blockIdx.x & 63;
    const int tb  = (pr << 1) | cs;
    const int c0  = ct << 2;
    const int t0  = tb * TB;

    const float4 z4 = *(const float4*)(la + c0);
    const float zz[4] = {z4.x, z4.y, z4.z, z4.w};
    float a[4], oma[4], ap[4], inva[4], invap[4];
    #pragma unroll
    for (int j = 0; j < 4; ++j) {
        a[j]     = clamp_sig(zz[j]);
        oma[j]   = 1.0f - a[j];
        const float l2a = log2f(a[j]);
        ap[j]    = exp2f((float)t0 * l2a);
        invap[j] = exp2f(-(float)t0 * l2a);  // inf ok: clamped to 1e8 below
        inva[j]  = 1.0f / a[j];
    }

    // exclusive prefix: ONE float4 read (K2 already scanned ws)
    const float4 p0 = *(const float4*)(ws + (size_t)(b * NTB + tb) * C_ + c0);
    float S[4] = {p0.x, p0.y, p0.z, p0.w};

    const float4* __restrict__ xp =
        (const float4*)(x + ((size_t)b * T_ + t0) * C_ + c0);
    float* __restrict__ yp = y + ((size_t)b * T_ + t0) * C_ + c0;

    #pragma unroll 8
    for (int i = 0; i < TB; ++i) {
        const float4 xv = xp[(size_t)i * (C_ >> 2)];
        const bool z0 = (t0 + i) == 0;
        S[0] = fmaf(xv.x, z0 ? 1.0f : ap[0] * oma[0], S[0]);
        S[1] = fmaf(xv.y, z0 ? 1.0f : ap[1] * oma[1], S[1]);
        S[2] = fmaf(xv.z, z0 ? 1.0f : ap[2] * oma[2], S[2]);
        S[3] = fmaf(xv.w, z0 ? 1.0f : ap[3] * oma[3], S[3]);
        // 1/max(a^t,1e-8) == min(a^-t, 1e8); inf clamps to 1e8 (matches EPS)
        f32x4 out;
        out.x = S[0] * fminf(invap[0], 1e8f);
        out.y = S[1] * fminf(invap[1], 1e8f);
        out.z = S[2] * fminf(invap[2], 1e8f);
        out.w = S[3] * fminf(invap[3], 1e8f);
        __builtin_nontemporal_store(out, (f32x4*)(yp + (size_t)i * C_));
        #pragma unroll
        for (int j = 0; j < 4; ++j) { ap[j] *= a[j]; invap[j] *= inva[j]; }
    }
}

extern "C" void kernel_launch(void* const* d_in, const int* in_sizes, int n_in,
                              void* d_out, int out_size, void* d_ws, size_t ws_size,
                              hipStream_t stream) {
    const float* x  = (const float*)d_in[0];   // [32, 2048, 512] fp32
    const float* la = (const float*)d_in[1];   // [512] fp32
    float* y  = (float*)d_out;                 // [32, 2048, 512] fp32
    float* ws = (float*)d_ws;                  // B*NTB*C*4 = 8 MB

    hipLaunchKernelGGL(ema_partials, dim3(B_ * (NTB / 2)), dim3(256), 0, stream,
                       x, la, ws);
    hipLaunchKernelGGL(ema_scanws,   dim3(B_ * C_ / 256),  dim3(256), 0, stream,
                       ws);
    hipLaunchKernelGGL(ema_apply,    dim3(B_ * (NTB / 2)), dim3(256), 0, stream,
                       x, la, ws, y);
}